// Round 9
// baseline (163.321 us; speedup 1.0000x reference)
//
#include <hip/hip_runtime.h>

// MetricBiasUpdater: B_next = clip(alpha*B_prev - beta*relu(pairdist(H@W^T)), -10, 10)
// B=4, N=2048, D=1024, K(geom)=32. Output fp32 [4,2048,2048].
//
// v10:
//  k0/k1: unchanged.
//  k2: two-phase per j-chunk. Evidence v2-v9: any structure needing N loaded
//      values at once compiles to N SERIAL HBM round-trips (allocator caps
//      VGPRs at ~60 and recycles via waits) -> constant 40 us. Fix: never
//      need more than one load per instruction.
//        Phase A (MFMA, tiny): dval[16][512] = beta*relu(qi+qj-2*Gi.Gj) -> LDS.
//        Phase B (stream): out = clamp(alpha*Bp - dval) -- 8 INDEPENDENT
//        load->valu->store iterations per thread, the proven-6.6TB/s pattern.

typedef __attribute__((ext_vector_type(8))) short short8;   // 8 bf16 (4 VGPRs)
typedef __attribute__((ext_vector_type(4))) short short4v;  // 4 bf16 (2 VGPRs)
typedef __attribute__((ext_vector_type(4))) float floatx4;  // 4 fp32 (4 VGPRs)

static __device__ __forceinline__ short bf16_bits(float f) {
    union { float f; unsigned int u; } v; v.f = f;
    unsigned int u = v.u;
    u += 0x7FFFu + ((u >> 16) & 1u);   // round-to-nearest-even
    return (short)(u >> 16);
}

static __device__ __forceinline__ float bf16_to_f32(unsigned short h) {
    union { unsigned int u; float f; } v; v.u = ((unsigned int)h) << 16;
    return v.f;
}

// ---------------------------------------------------------------------------
// Kernel 0: W fp32 [32][1024] -> bf16.
// ---------------------------------------------------------------------------
__global__ __launch_bounds__(256) void k0_wcast(const float* __restrict__ W,
                                                short* __restrict__ Wb) {
    const int f = blockIdx.x * 256 + threadIdx.x;   // 8192 float4 chunks
    const float4 v = *(const float4*)(W + (long)f * 4);
    short4v s;
    s[0] = bf16_bits(v.x); s[1] = bf16_bits(v.y);
    s[2] = bf16_bits(v.z); s[3] = bf16_bits(v.w);
    *(short4v*)(Wb + (long)f * 4) = s;
}

// ---------------------------------------------------------------------------
// Kernel 1: G[row][k] = sum_d H[row][d] * W[k][d]  (rows = 8192 flat, k = 32)
// ---------------------------------------------------------------------------
__global__ __launch_bounds__(256) void k1_proj(const float* __restrict__ H,
                                               const short* __restrict__ Wb,
                                               unsigned short* __restrict__ G,
                                               float* __restrict__ Q) {
    const int blk  = blockIdx.x;        // 512 blocks x 16 rows
    const int t    = threadIdx.x;
    const int w    = t >> 6;            // wave id -> K quarter
    const int lane = t & 63;
    const int m    = lane & 15;         // A row within tile / B column n
    const int quad = lane >> 4;

    __shared__ short sH[16 * 1032];     // 16 rows x 1024 bf16, stride 1032 (33 KB)

    // ---- coalesced stage: 2048 8-float chunks, 8 per thread ----
    const float* Hb = H + (long)blk * 16384;
    #pragma unroll
    for (int it = 0; it < 8; ++it) {
        const int f  = t + it * 256;    // 0..2047
        const int r  = f >> 7;          // row 0..15
        const int c8 = f & 127;         // 8-float chunk within row
        const float4 v0 = *(const float4*)(Hb + r * 1024 + c8 * 8);
        const float4 v1 = *(const float4*)(Hb + r * 1024 + c8 * 8 + 4);
        short8 sv;
        sv[0] = bf16_bits(v0.x); sv[1] = bf16_bits(v0.y);
        sv[2] = bf16_bits(v0.z); sv[3] = bf16_bits(v0.w);
        sv[4] = bf16_bits(v1.x); sv[5] = bf16_bits(v1.y);
        sv[6] = bf16_bits(v1.z); sv[7] = bf16_bits(v1.w);
        *(short8*)&sH[r * 1032 + c8 * 8] = sv;
    }
    __syncthreads();

    const int kq = w * 256 + quad * 8;  // this lane's k base (frag: k = quad*8 + j)
    const short* wb0 = Wb + (long)m * 1024 + kq;          // n-tile 0: n = m
    const short* wb1 = Wb + (long)(m + 16) * 1024 + kq;   // n-tile 1: n = m+16

    floatx4 acc0 = {0.f, 0.f, 0.f, 0.f};
    floatx4 acc1 = {0.f, 0.f, 0.f, 0.f};

    short8 b0 = *(const short8*)wb0;
    short8 b1 = *(const short8*)wb1;

    #pragma unroll
    for (int s = 0; s < 8; ++s) {
        short8 nb0, nb1;
        if (s < 7) {                    // prefetch next W-step while MFMA runs
            nb0 = *(const short8*)(wb0 + (s + 1) * 32);
            nb1 = *(const short8*)(wb1 + (s + 1) * 32);
        }
        const short8 af = *(const short8*)&sH[m * 1032 + kq + s * 32];
        acc0 = __builtin_amdgcn_mfma_f32_16x16x32_bf16(af, b0, acc0, 0, 0, 0);
        acc1 = __builtin_amdgcn_mfma_f32_16x16x32_bf16(af, b1, acc1, 0, 0, 0);
        if (s < 7) { b0 = nb0; b1 = nb1; }
    }

    // reduce K-quarter partials across the 4 waves.
    // C/D layout: col = lane&15 (=n), row = quad*4 + reg (=m)  (measured m89)
    __shared__ float red[4][16][32];
    #pragma unroll
    for (int r = 0; r < 4; ++r) {
        red[w][quad * 4 + r][m]      = acc0[r];
        red[w][quad * 4 + r][m + 16] = acc1[r];
    }
    __syncthreads();
    for (int e = t; e < 512; e += 256) {
        const int mm = e >> 5, nn = e & 31;
        float v = red[0][mm][nn] + red[1][mm][nn] + red[2][mm][nn] + red[3][mm][nn];
        const unsigned short hb = (unsigned short)bf16_bits(v);
        G[(long)(blk * 16 + mm) * 32 + nn] = hb;
        red[0][mm][nn] = bf16_to_f32(hb);   // Q from ROUNDED values: dist(i,i) ~ 0
    }
    __syncthreads();
    if (t < 16) {
        float s = 0.f;
        #pragma unroll
        for (int nn = 0; nn < 32; ++nn) { const float v = red[0][t][nn]; s += v * v; }
        Q[blk * 16 + t] = s;
    }
}

// ---------------------------------------------------------------------------
// Kernel 2: out[b][i][j] = clip(alpha*Bp - beta*relu(q[i]+q[j]-2*G[i].G[j]))
// Block = 16 i-rows x full 2048 j, processed in 4 chunks of 512 j.
// Phase A: 8 MFMA/wave -> dval[16][512] in LDS (L2-hot 1KB frag loads).
// Phase B: pure stream: 8 independent {ld float4, 12 VALU, st float4}/thread.
// Grid 512 blocks (2/CU). LDS 33 KB.
// ---------------------------------------------------------------------------
__global__ __launch_bounds__(256) void k2_update(const float* __restrict__ Bp,
                                                 const unsigned short* __restrict__ G,
                                                 const float* __restrict__ Q,
                                                 const float* __restrict__ alphap,
                                                 const float* __restrict__ betap,
                                                 float* __restrict__ out) {
    __shared__ float sD[16 * 516];   // dval chunk [16][512], row stride 516 (2-way max)

    const int b  = blockIdx.y;
    const int i0 = blockIdx.x * 16;
    const int t  = threadIdx.x;
    const int w    = t >> 6;
    const int lane = t & 63;
    const int m    = lane & 15;      // i-local (D column)
    const int quad = lane >> 4;      // j sub-quad (D row group)

    const short* Gg = (const short*)G;
    // B-frag (i-side): Gi row i0+m, k-slice quad*8 -- same for all 4 waves
    const short8 bfi = *(const short8*)&Gg[((long)(b * 2048 + i0 + m)) * 32 + quad * 8];
    const float qi_m  = Q[b * 2048 + i0 + m];   // qi for this lane's column i=i0+m
    const float alpha = alphap[0];
    const float beta  = betap[0];

    // stream-phase indexing: thread owns row sr, 8 float4 slots per chunk
    const int sr = t >> 4;           // 0..15
    const int sc = t & 15;           // base float4 index
    const float* bprow = Bp  + ((long)b * 2048 + i0 + sr) * 2048;
    float*       orow  = out + ((long)b * 2048 + i0 + sr) * 2048;

    for (int c = 0; c < 4; ++c) {
        // ============ phase A: dval[16][512] via MFMA ============
        // wave w owns j-local [w*128, w*128+128): 8 tiles of 16
        #pragma unroll
        for (int jt = 0; jt < 8; ++jt) {
            const int jl = w * 128 + jt * 16;       // j local to chunk
            const int jg = c * 512 + jl;            // j global
            const short8 afj = *(const short8*)&Gg[((long)(b * 2048 + jg + m)) * 32 + quad * 8];
            floatx4 z = {0.f, 0.f, 0.f, 0.f};
            const floatx4 acc = __builtin_amdgcn_mfma_f32_16x16x32_bf16(afj, bfi, z, 0, 0, 0);
            const float4 qj = *(const float4*)&Q[b * 2048 + jg + quad * 4];
            // D layout: row = quad*4+r (j-local-in-tile), col = m (i)
            float4 dv;
            dv.x = beta * fmaxf(qi_m + qj.x - 2.f * acc[0], 0.f);
            dv.y = beta * fmaxf(qi_m + qj.y - 2.f * acc[1], 0.f);
            dv.z = beta * fmaxf(qi_m + qj.z - 2.f * acc[2], 0.f);
            dv.w = beta * fmaxf(qi_m + qj.w - 2.f * acc[3], 0.f);
            *(float4*)&sD[m * 516 + jl + quad * 4] = dv;
        }
        __syncthreads();

        // ============ phase B: stream 16 rows x 512 cols ============
        #pragma unroll
        for (int k = 0; k < 8; ++k) {
            const int col4 = sc + k * 16;           // float4 idx within chunk
            const float4 bv = *(const float4*)(bprow + c * 512 + col4 * 4);
            const float4 dv = *(const float4*)&sD[sr * 516 + col4 * 4];
            float4 ov;
            ov.x = fminf(fmaxf(alpha * bv.x - dv.x, -10.f), 10.f);
            ov.y = fminf(fmaxf(alpha * bv.y - dv.y, -10.f), 10.f);
            ov.z = fminf(fmaxf(alpha * bv.z - dv.z, -10.f), 10.f);
            ov.w = fminf(fmaxf(alpha * bv.w - dv.w, -10.f), 10.f);
            *(float4*)(orow + c * 512 + col4 * 4) = ov;
        }
        __syncthreads();   // sD reused next chunk
    }
}

extern "C" void kernel_launch(void* const* d_in, const int* in_sizes, int n_in,
                              void* d_out, int out_size, void* d_ws, size_t ws_size,
                              hipStream_t stream) {
    const float* H     = (const float*)d_in[0];   // [4,2048,1024]
    const float* Bp    = (const float*)d_in[1];   // [4,2048,2048]
    const float* W     = (const float*)d_in[2];   // [32,1024]
    const float* alpha = (const float*)d_in[3];
    const float* beta  = (const float*)d_in[4];
    float* out = (float*)d_out;

    unsigned short* G = (unsigned short*)d_ws;          // [8192][32] bf16 = 512 KB
    float* Q  = (float*)((char*)d_ws + 8192 * 32 * 2);  // [8192] fp32 = 32 KB
    short* Wb = (short*)((char*)d_ws + 8192 * 32 * 2 + 8192 * 4);  // [32][1024] bf16

    k0_wcast<<<32, 256, 0, stream>>>(W, Wb);
    k1_proj<<<512, 256, 0, stream>>>(H, Wb, G, Q);

    dim3 g2(128, 4);                  // i-tiles(16), batch
    k2_update<<<g2, 256, 0, stream>>>(Bp, G, Q, alpha, beta, out);
}

// Round 10
// 162.578 us; speedup vs baseline: 1.0046x; 1.0046x over previous
//
#include <hip/hip_runtime.h>

// MetricBiasUpdater: B_next = clip(alpha*B_prev - beta*relu(pairdist(H@W^T)), -10, 10)
// B=4, N=2048, D=1024, K(geom)=32. Output fp32 [4,2048,2048].
//
// v11:
//  k0/k1: unchanged.
//  k2: TLP-maximized. Little's-law audit of v2-v10: every variant ran at
//      waves/CU x ~1KB in flight (compiler serializes reads to ~1/wave;
//      9 rounds of ILP attempts failed), so BW = occupancy-limited:
//      12 waves/CU -> 2.5 TB/s. Fix: tiny per-wave state (one 16x16 j-tile
//      per iteration, ~40 VGPR), no LDS, no barriers, launch_bounds(256,8)
//      -> 8 blocks/CU = 32 waves/CU = ~8 MB reads in flight = BW-saturated
//      even with fully serialized per-thread loads. Writes never stall.

typedef __attribute__((ext_vector_type(8))) short short8;   // 8 bf16 (4 VGPRs)
typedef __attribute__((ext_vector_type(4))) short short4v;  // 4 bf16 (2 VGPRs)
typedef __attribute__((ext_vector_type(4))) float floatx4;  // 4 fp32 (4 VGPRs)

static __device__ __forceinline__ short bf16_bits(float f) {
    union { float f; unsigned int u; } v; v.f = f;
    unsigned int u = v.u;
    u += 0x7FFFu + ((u >> 16) & 1u);   // round-to-nearest-even
    return (short)(u >> 16);
}

static __device__ __forceinline__ float bf16_to_f32(unsigned short h) {
    union { unsigned int u; float f; } v; v.u = ((unsigned int)h) << 16;
    return v.f;
}

// ---------------------------------------------------------------------------
// Kernel 0: W fp32 [32][1024] -> bf16.
// ---------------------------------------------------------------------------
__global__ __launch_bounds__(256) void k0_wcast(const float* __restrict__ W,
                                                short* __restrict__ Wb) {
    const int f = blockIdx.x * 256 + threadIdx.x;   // 8192 float4 chunks
    const float4 v = *(const float4*)(W + (long)f * 4);
    short4v s;
    s[0] = bf16_bits(v.x); s[1] = bf16_bits(v.y);
    s[2] = bf16_bits(v.z); s[3] = bf16_bits(v.w);
    *(short4v*)(Wb + (long)f * 4) = s;
}

// ---------------------------------------------------------------------------
// Kernel 1: G[row][k] = sum_d H[row][d] * W[k][d]  (rows = 8192 flat, k = 32)
// ---------------------------------------------------------------------------
__global__ __launch_bounds__(256) void k1_proj(const float* __restrict__ H,
                                               const short* __restrict__ Wb,
                                               unsigned short* __restrict__ G,
                                               float* __restrict__ Q) {
    const int blk  = blockIdx.x;        // 512 blocks x 16 rows
    const int t    = threadIdx.x;
    const int w    = t >> 6;            // wave id -> K quarter
    const int lane = t & 63;
    const int m    = lane & 15;         // A row within tile / B column n
    const int quad = lane >> 4;

    __shared__ short sH[16 * 1032];     // 16 rows x 1024 bf16, stride 1032 (33 KB)

    // ---- coalesced stage: 2048 8-float chunks, 8 per thread ----
    const float* Hb = H + (long)blk * 16384;
    #pragma unroll
    for (int it = 0; it < 8; ++it) {
        const int f  = t + it * 256;    // 0..2047
        const int r  = f >> 7;          // row 0..15
        const int c8 = f & 127;         // 8-float chunk within row
        const float4 v0 = *(const float4*)(Hb + r * 1024 + c8 * 8);
        const float4 v1 = *(const float4*)(Hb + r * 1024 + c8 * 8 + 4);
        short8 sv;
        sv[0] = bf16_bits(v0.x); sv[1] = bf16_bits(v0.y);
        sv[2] = bf16_bits(v0.z); sv[3] = bf16_bits(v0.w);
        sv[4] = bf16_bits(v1.x); sv[5] = bf16_bits(v1.y);
        sv[6] = bf16_bits(v1.z); sv[7] = bf16_bits(v1.w);
        *(short8*)&sH[r * 1032 + c8 * 8] = sv;
    }
    __syncthreads();

    const int kq = w * 256 + quad * 8;  // this lane's k base (frag: k = quad*8 + j)
    const short* wb0 = Wb + (long)m * 1024 + kq;          // n-tile 0: n = m
    const short* wb1 = Wb + (long)(m + 16) * 1024 + kq;   // n-tile 1: n = m+16

    floatx4 acc0 = {0.f, 0.f, 0.f, 0.f};
    floatx4 acc1 = {0.f, 0.f, 0.f, 0.f};

    short8 b0 = *(const short8*)wb0;
    short8 b1 = *(const short8*)wb1;

    #pragma unroll
    for (int s = 0; s < 8; ++s) {
        short8 nb0, nb1;
        if (s < 7) {                    // prefetch next W-step while MFMA runs
            nb0 = *(const short8*)(wb0 + (s + 1) * 32);
            nb1 = *(const short8*)(wb1 + (s + 1) * 32);
        }
        const short8 af = *(const short8*)&sH[m * 1032 + kq + s * 32];
        acc0 = __builtin_amdgcn_mfma_f32_16x16x32_bf16(af, b0, acc0, 0, 0, 0);
        acc1 = __builtin_amdgcn_mfma_f32_16x16x32_bf16(af, b1, acc1, 0, 0, 0);
        if (s < 7) { b0 = nb0; b1 = nb1; }
    }

    // reduce K-quarter partials across the 4 waves.
    // C/D layout: col = lane&15 (=n), row = quad*4 + reg (=m)  (measured m89)
    __shared__ float red[4][16][32];
    #pragma unroll
    for (int r = 0; r < 4; ++r) {
        red[w][quad * 4 + r][m]      = acc0[r];
        red[w][quad * 4 + r][m + 16] = acc1[r];
    }
    __syncthreads();
    for (int e = t; e < 512; e += 256) {
        const int mm = e >> 5, nn = e & 31;
        float v = red[0][mm][nn] + red[1][mm][nn] + red[2][mm][nn] + red[3][mm][nn];
        const unsigned short hb = (unsigned short)bf16_bits(v);
        G[(long)(blk * 16 + mm) * 32 + nn] = hb;
        red[0][mm][nn] = bf16_to_f32(hb);   // Q from ROUNDED values: dist(i,i) ~ 0
    }
    __syncthreads();
    if (t < 16) {
        float s = 0.f;
        #pragma unroll
        for (int nn = 0; nn < 32; ++nn) { const float v = red[0][t][nn]; s += v * v; }
        Q[blk * 16 + t] = s;
    }
}

// ---------------------------------------------------------------------------
// Kernel 2: out[b][i][j] = clip(alpha*Bp - beta*relu(q[i]+q[j]-2*G[i].G[j]))
// TLP design: wave = 16(i) x 128(j), looping 8 single 16x16 j-tiles.
// Per iteration: {Gj frag (L2), qj 64B, Bp 1KB} -> 1 MFMA -> epilogue -> store.
// No LDS, no barriers, ~40 VGPR; launch_bounds(256,8) -> 32 waves/CU.
// Grid 2048 blocks = exactly 8 blocks/CU resident.
// ---------------------------------------------------------------------------
__global__ __launch_bounds__(256, 8) void k2_update(const float* __restrict__ Bp,
                                                    const unsigned short* __restrict__ G,
                                                    const float* __restrict__ Q,
                                                    const float* __restrict__ alphap,
                                                    const float* __restrict__ betap,
                                                    float* __restrict__ out) {
    const int b  = blockIdx.z;
    const int i0 = blockIdx.y * 64;
    const int jc = blockIdx.x;        // j-chunk of 128
    const int t  = threadIdx.x;
    const int w    = t >> 6;          // wave -> i rows [w*16, w*16+16)
    const int lane = t & 63;
    const int m    = lane & 15;       // i within wave tile (D column)
    const int quad = lane >> 4;       // j sub-quad (D row group)

    const int i = i0 + w * 16 + m;
    const long rowoff = ((long)b * 2048 + i) * 2048 + jc * 128;

    const short* Gg = (const short*)G;
    // B-frag (i-side): lane holds Gi row i, k = quad*8..+8
    const short8 bfi = *(const short8*)&Gg[((long)(b * 2048 + i)) * 32 + quad * 8];
    const float qi    = Q[b * 2048 + i];
    const float alpha = alphap[0];
    const float beta  = betap[0];

    const float* bpp    = Bp + rowoff + quad * 4;
    float*       op     = out + rowoff + quad * 4;
    const short* gjbase = Gg + ((long)(b * 2048 + jc * 128 + m)) * 32 + quad * 8;
    const float* qjbase = Q + (long)b * 2048 + jc * 128 + quad * 4;

    #pragma unroll
    for (int jt = 0; jt < 8; ++jt) {
        // A-frag (j-side): lane holds Gj row jc*128+jt*16+m, same k slice
        const short8  afj = *(const short8*)(gjbase + (long)jt * 16 * 32);
        const floatx4 qj  = *(const floatx4*)(qjbase + jt * 16);
        const floatx4 bv  = *(const floatx4*)(bpp + jt * 16);

        floatx4 z = {0.f, 0.f, 0.f, 0.f};
        // D layout: row = quad*4+r = j within tile, col = m = i
        const floatx4 acc = __builtin_amdgcn_mfma_f32_16x16x32_bf16(afj, bfi, z, 0, 0, 0);

        floatx4 ov;
        #pragma unroll
        for (int r = 0; r < 4; ++r) {
            float d = qi + qj[r] - 2.f * acc[r];
            d = fmaxf(d, 0.f);
            ov[r] = fminf(fmaxf(alpha * bv[r] - beta * d, -10.f), 10.f);
        }
        *(floatx4*)(op + jt * 16) = ov;
    }
}

extern "C" void kernel_launch(void* const* d_in, const int* in_sizes, int n_in,
                              void* d_out, int out_size, void* d_ws, size_t ws_size,
                              hipStream_t stream) {
    const float* H     = (const float*)d_in[0];   // [4,2048,1024]
    const float* Bp    = (const float*)d_in[1];   // [4,2048,2048]
    const float* W     = (const float*)d_in[2];   // [32,1024]
    const float* alpha = (const float*)d_in[3];
    const float* beta  = (const float*)d_in[4];
    float* out = (float*)d_out;

    unsigned short* G = (unsigned short*)d_ws;          // [8192][32] bf16 = 512 KB
    float* Q  = (float*)((char*)d_ws + 8192 * 32 * 2);  // [8192] fp32 = 32 KB
    short* Wb = (short*)((char*)d_ws + 8192 * 32 * 2 + 8192 * 4);  // [32][1024] bf16

    k0_wcast<<<32, 256, 0, stream>>>(W, Wb);
    k1_proj<<<512, 256, 0, stream>>>(H, Wb, G, Q);

    dim3 g2(16, 32, 4);               // j-chunks(128), i-tiles(64), batch
    k2_update<<<g2, 256, 0, stream>>>(Bp, G, Q, alpha, beta, out);
}

// Round 12
// 161.012 us; speedup vs baseline: 1.0143x; 1.0097x over previous
//
#include <hip/hip_runtime.h>

// MetricBiasUpdater: B_next = clip(alpha*B_prev - beta*relu(pairdist(H@W^T)), -10, 10)
// B=4, N=2048, D=1024, K(geom)=32. Output fp32 [4,2048,2048].
//
// v12b (v12 + explicit counted vmcnt waits; round-11 bench was an infra
//       failure, kernel logic re-audited and hardened):
//  k0/k1: unchanged.
//  k2: DMA-pipelined. v2-v11 evidence: any Bp path through VGPRs is
//      serialized by the register allocator (VGPR capped 32-88, loads
//      rotated into load->use chains) -> 2.5 TB/s at EVERY occupancy.
//      global_load_lds uses ZERO VGPRs -> allocator can't serialize it.
//      Per 64x64 chunk: phase A computes dval->LDS via MFMA (G in L2);
//      next chunk's Bp tile DMAs into the other buffer; explicit
//      s_waitcnt vmcnt(4) retires everything EXCEPT the 4 prefetch DMAs
//      (newest) before the barrier -> correctness guaranteed by counting,
//      prefetch stays in flight. RAW s_barrier + lgkmcnt(0) only --
//      __syncthreads would drain vmcnt(0) and kill the pipeline.

typedef __attribute__((ext_vector_type(8))) short short8;   // 8 bf16 (4 VGPRs)
typedef __attribute__((ext_vector_type(4))) short short4v;  // 4 bf16 (2 VGPRs)
typedef __attribute__((ext_vector_type(4))) float floatx4;  // 4 fp32 (4 VGPRs)

static __device__ __forceinline__ short bf16_bits(float f) {
    union { float f; unsigned int u; } v; v.f = f;
    unsigned int u = v.u;
    u += 0x7FFFu + ((u >> 16) & 1u);   // round-to-nearest-even
    return (short)(u >> 16);
}

static __device__ __forceinline__ float bf16_to_f32(unsigned short h) {
    union { unsigned int u; float f; } v; v.u = ((unsigned int)h) << 16;
    return v.f;
}

// ---------------------------------------------------------------------------
// Kernel 0: W fp32 [32][1024] -> bf16.
// ---------------------------------------------------------------------------
__global__ __launch_bounds__(256) void k0_wcast(const float* __restrict__ W,
                                                short* __restrict__ Wb) {
    const int f = blockIdx.x * 256 + threadIdx.x;   // 8192 float4 chunks
    const float4 v = *(const float4*)(W + (long)f * 4);
    short4v s;
    s[0] = bf16_bits(v.x); s[1] = bf16_bits(v.y);
    s[2] = bf16_bits(v.z); s[3] = bf16_bits(v.w);
    *(short4v*)(Wb + (long)f * 4) = s;
}

// ---------------------------------------------------------------------------
// Kernel 1: G[row][k] = sum_d H[row][d] * W[k][d]  (rows = 8192 flat, k = 32)
// ---------------------------------------------------------------------------
__global__ __launch_bounds__(256) void k1_proj(const float* __restrict__ H,
                                               const short* __restrict__ Wb,
                                               unsigned short* __restrict__ G,
                                               float* __restrict__ Q) {
    const int blk  = blockIdx.x;        // 512 blocks x 16 rows
    const int t    = threadIdx.x;
    const int w    = t >> 6;            // wave id -> K quarter
    const int lane = t & 63;
    const int m    = lane & 15;         // A row within tile / B column n
    const int quad = lane >> 4;

    __shared__ short sH[16 * 1032];     // 16 rows x 1024 bf16, stride 1032 (33 KB)

    // ---- coalesced stage: 2048 8-float chunks, 8 per thread ----
    const float* Hb = H + (long)blk * 16384;
    #pragma unroll
    for (int it = 0; it < 8; ++it) {
        const int f  = t + it * 256;    // 0..2047
        const int r  = f >> 7;          // row 0..15
        const int c8 = f & 127;         // 8-float chunk within row
        const float4 v0 = *(const float4*)(Hb + r * 1024 + c8 * 8);
        const float4 v1 = *(const float4*)(Hb + r * 1024 + c8 * 8 + 4);
        short8 sv;
        sv[0] = bf16_bits(v0.x); sv[1] = bf16_bits(v0.y);
        sv[2] = bf16_bits(v0.z); sv[3] = bf16_bits(v0.w);
        sv[4] = bf16_bits(v1.x); sv[5] = bf16_bits(v1.y);
        sv[6] = bf16_bits(v1.z); sv[7] = bf16_bits(v1.w);
        *(short8*)&sH[r * 1032 + c8 * 8] = sv;
    }
    __syncthreads();

    const int kq = w * 256 + quad * 8;  // this lane's k base (frag: k = quad*8 + j)
    const short* wb0 = Wb + (long)m * 1024 + kq;          // n-tile 0: n = m
    const short* wb1 = Wb + (long)(m + 16) * 1024 + kq;   // n-tile 1: n = m+16

    floatx4 acc0 = {0.f, 0.f, 0.f, 0.f};
    floatx4 acc1 = {0.f, 0.f, 0.f, 0.f};

    short8 b0 = *(const short8*)wb0;
    short8 b1 = *(const short8*)wb1;

    #pragma unroll
    for (int s = 0; s < 8; ++s) {
        short8 nb0, nb1;
        if (s < 7) {                    // prefetch next W-step while MFMA runs
            nb0 = *(const short8*)(wb0 + (s + 1) * 32);
            nb1 = *(const short8*)(wb1 + (s + 1) * 32);
        }
        const short8 af = *(const short8*)&sH[m * 1032 + kq + s * 32];
        acc0 = __builtin_amdgcn_mfma_f32_16x16x32_bf16(af, b0, acc0, 0, 0, 0);
        acc1 = __builtin_amdgcn_mfma_f32_16x16x32_bf16(af, b1, acc1, 0, 0, 0);
        if (s < 7) { b0 = nb0; b1 = nb1; }
    }

    // reduce K-quarter partials across the 4 waves.
    // C/D layout: col = lane&15 (=n), row = quad*4 + reg (=m)  (measured m89)
    __shared__ float red[4][16][32];
    #pragma unroll
    for (int r = 0; r < 4; ++r) {
        red[w][quad * 4 + r][m]      = acc0[r];
        red[w][quad * 4 + r][m + 16] = acc1[r];
    }
    __syncthreads();
    for (int e = t; e < 512; e += 256) {
        const int mm = e >> 5, nn = e & 31;
        float v = red[0][mm][nn] + red[1][mm][nn] + red[2][mm][nn] + red[3][mm][nn];
        const unsigned short hb = (unsigned short)bf16_bits(v);
        G[(long)(blk * 16 + mm) * 32 + nn] = hb;
        red[0][mm][nn] = bf16_to_f32(hb);   // Q from ROUNDED values: dist(i,i) ~ 0
    }
    __syncthreads();
    if (t < 16) {
        float s = 0.f;
        #pragma unroll
        for (int nn = 0; nn < 32; ++nn) { const float v = red[0][t][nn]; s += v * v; }
        Q[blk * 16 + t] = s;
    }
}

// ---------------------------------------------------------------------------
// Kernel 2: out[b][i][j] = clip(alpha*Bp - beta*relu(q[i]+q[j]-2*G[i].G[j]))
// Block = 64 i x 512 j (8 chunks of 64x64), 4 waves. Per chunk:
//   A: 4 MFMA/wave -> dval[64][68] LDS.  DMA c+1 Bp tile -> sBp[buf^1]
//      (zero VGPRs; stays in flight across barriers).
//   explicit vmcnt(4): retire all but the 4 newest ops (= the prefetch).
//   B: linear LDS reads + fused EMA/clamp + coalesced stores.
// Grid 512 blocks (2/CU). LDS ~49.5 KB.
// ---------------------------------------------------------------------------
__global__ __launch_bounds__(256) void k2_update(const float* __restrict__ Bp,
                                                 const unsigned short* __restrict__ G,
                                                 const float* __restrict__ Q,
                                                 const float* __restrict__ alphap,
                                                 const float* __restrict__ betap,
                                                 float* __restrict__ out) {
    __shared__ float sBp[2][4096];     // Bp chunk [64 i][64 j] fp32, 16 KB x2
    __shared__ float sDv[64 * 68];     // dval [64 i][68] padded, 17 KB

    const int b  = blockIdx.z;
    const int i0 = blockIdx.y * 64;
    const int J0 = blockIdx.x * 512;   // j-span
    const int t  = threadIdx.x;
    const int w    = t >> 6;
    const int lane = t & 63;
    const int m    = lane & 15;        // i within wave tile (D column)
    const int quad = lane >> 4;        // j sub-quad (D row group)

    const short* Gg = (const short*)G;
    // i-side fragment + qi (L2-hot)
    const short8 bfi = *(const short8*)&Gg[((long)(b * 2048 + i0 + w * 16 + m)) * 32 + quad * 8];
    const float qi    = Q[b * 2048 + i0 + w * 16 + m];
    const float alpha = alphap[0];
    const float beta  = betap[0];

    // DMA source: wave w stages i-rows [w*16, w*16+16), 4 rows per 1KB instr.
    // lane l: row = n*4 + (l>>4), 16B at j-dword (l&15)*4.
    const float* dma_base = Bp + ((long)(b * 2048 + i0 + w * 16 + (lane >> 4))) * 2048
                               + J0 + (lane & 15) * 4;

#define GLOAD_LDS(gsrc, ldst) \
    __builtin_amdgcn_global_load_lds((const __attribute__((address_space(1))) void*)(gsrc), \
                                     (__attribute__((address_space(3))) void*)(ldst), 16, 0, 0)

    // ---- prologue: DMA chunk 0 into buf 0 (4 x 1KB per wave, zero VGPRs) ----
    #pragma unroll
    for (int n = 0; n < 4; ++n)
        GLOAD_LDS(dma_base + n * 4 * 2048, &sBp[0][w * 1024 + n * 256]);
    __builtin_amdgcn_sched_barrier(0);

    for (int c = 0; c < 8; ++c) {
        const int cur = c & 1;
        const int jcg = J0 + c * 64;

        // ================ phase A: dval chunk via MFMA ================
        #pragma unroll
        for (int jt = 0; jt < 4; ++jt) {
            const short8 afj = *(const short8*)&Gg[((long)(b * 2048 + jcg + jt * 16 + m)) * 32 + quad * 8];
            const floatx4 qj = *(const floatx4*)&Q[b * 2048 + jcg + jt * 16 + quad * 4];
            floatx4 z = {0.f, 0.f, 0.f, 0.f};
            const floatx4 acc = __builtin_amdgcn_mfma_f32_16x16x32_bf16(afj, bfi, z, 0, 0, 0);
            // D: row = quad*4+r = j-in-tile, col = m = i-in-wave-tile
            floatx4 dv;
            #pragma unroll
            for (int r = 0; r < 4; ++r)
                dv[r] = beta * fmaxf(qi + qj[r] - 2.f * acc[r], 0.f);
            *(floatx4*)&sDv[(w * 16 + m) * 68 + jt * 16 + quad * 4] = dv;
        }

        // ---- issue DMA for chunk c+1 (stays in flight through barrier+B) ----
        __builtin_amdgcn_sched_barrier(0);
        if (c < 7) {
            #pragma unroll
            for (int n = 0; n < 4; ++n)
                GLOAD_LDS(dma_base + n * 4 * 2048 + (c + 1) * 64,
                          &sBp[cur ^ 1][w * 1024 + n * 256]);
        }
        __builtin_amdgcn_sched_barrier(0);

        // ---- counted drain: retire all but the 4 newest (prefetch DMAs).
        //      Guarantees chunk-c DMA + all loads/stores older are complete.
        if (c < 7) { asm volatile("s_waitcnt vmcnt(4)" ::: "memory"); }
        else       { asm volatile("s_waitcnt vmcnt(0)" ::: "memory"); }
        __builtin_amdgcn_sched_barrier(0);
        // ---- barrier WITHOUT full vmcnt drain: dval ds_writes visible ----
        asm volatile("s_waitcnt lgkmcnt(0)" ::: "memory");
        __builtin_amdgcn_sched_barrier(0);
        __builtin_amdgcn_s_barrier();
        __builtin_amdgcn_sched_barrier(0);

        // ================ phase B: stream 64x64 out ================
        // thread t, k: LDS float offset t*4 + k*1024 -> row (t>>4)+16k,
        // j-dword (t&15)*4. Coalesced 256B segments per row.
        #pragma unroll
        for (int k = 0; k < 4; ++k) {
            const int row = (t >> 4) + k * 16;
            const float4 bv = *(const float4*)&sBp[cur][t * 4 + k * 1024];
            const float4 dv = *(const float4*)&sDv[row * 68 + (t & 15) * 4];
            float4 ov;
            ov.x = fminf(fmaxf(alpha * bv.x - dv.x, -10.f), 10.f);
            ov.y = fminf(fmaxf(alpha * bv.y - dv.y, -10.f), 10.f);
            ov.z = fminf(fmaxf(alpha * bv.z - dv.z, -10.f), 10.f);
            ov.w = fminf(fmaxf(alpha * bv.w - dv.w, -10.f), 10.f);
            *(float4*)(out + ((long)(b * 2048 + i0 + row)) * 2048 + jcg + (t & 15) * 4) = ov;
        }

        // ---- end barrier (sDv / sBp reuse), again no vmcnt drain ----
        asm volatile("s_waitcnt lgkmcnt(0)" ::: "memory");
        __builtin_amdgcn_sched_barrier(0);
        __builtin_amdgcn_s_barrier();
        __builtin_amdgcn_sched_barrier(0);
    }
#undef GLOAD_LDS
}

extern "C" void kernel_launch(void* const* d_in, const int* in_sizes, int n_in,
                              void* d_out, int out_size, void* d_ws, size_t ws_size,
                              hipStream_t stream) {
    const float* H     = (const float*)d_in[0];   // [4,2048,1024]
    const float* Bp    = (const float*)d_in[1];   // [4,2048,2048]
    const float* W     = (const float*)d_in[2];   // [32,1024]
    const float* alpha = (const float*)d_in[3];
    const float* beta  = (const float*)d_in[4];
    float* out = (float*)d_out;

    unsigned short* G = (unsigned short*)d_ws;          // [8192][32] bf16 = 512 KB
    float* Q  = (float*)((char*)d_ws + 8192 * 32 * 2);  // [8192] fp32 = 32 KB
    short* Wb = (short*)((char*)d_ws + 8192 * 32 * 2 + 8192 * 4);  // [32][1024] bf16

    k0_wcast<<<32, 256, 0, stream>>>(W, Wb);
    k1_proj<<<512, 256, 0, stream>>>(H, Wb, G, Q);

    dim3 g2(4, 32, 4);                // j-spans(512), i-tiles(64), batch
    k2_update<<<g2, 256, 0, stream>>>(Bp, G, Q, alpha, beta, out);
}